// Round 13
// baseline (114.515 us; speedup 1.0000x reference)
//
#include <hip/hip_runtime.h>
#include <hip/hip_bf16.h>

#define NN 8192
#define DD 512
#define HH 256
#define LL 64
#define EE 262144
#define CAP 96
#define DSTR 260   // decode LDS row stride (floats): 16x260 f32 = 16.6 KB

typedef __attribute__((ext_vector_type(8))) short short8;
typedef __attribute__((ext_vector_type(4))) float f32x4;

__device__ __forceinline__ unsigned short f2b(float f) {
    __hip_bfloat16 b = __float2bfloat16(f);
    return *(unsigned short*)&b;
}
__device__ __forceinline__ float b2f(unsigned short u) {
    union { unsigned int i; float f; } c; c.i = ((unsigned int)u) << 16; return c.f;
}

// ---------------- K1 prep: zero cnt + cast x->bf16 + transpose/cast W1,W2 ----------------
__global__ __launch_bounds__(256) void k_prep(const float* __restrict__ x,
                                              const float* __restrict__ w1,
                                              const float* __restrict__ w2,
                                              unsigned short* __restrict__ xb,
                                              unsigned short* __restrict__ w1t,
                                              unsigned short* __restrict__ w2t,
                                              int* __restrict__ cnt) {
    const int gtid = blockIdx.x * 256 + threadIdx.x;  // 0..524287
#pragma unroll
    for (int it = 0; it < 2; ++it) {
        int i = gtid + it * 524288;
        float4 v = ((const float4*)x)[i];
        ushort4 o; o.x = f2b(v.x); o.y = f2b(v.y); o.z = f2b(v.z); o.w = f2b(v.w);
        ((ushort4*)xb)[i] = o;
    }
    if (gtid < NN / 4) ((int4*)cnt)[gtid] = make_int4(0, 0, 0, 0);
    if (gtid < 16384) {  // w1t[256][512]
        int c = gtid & 255, kg = gtid >> 8;
        short8 v;
#pragma unroll
        for (int j = 0; j < 8; ++j) v[j] = (short)f2b(w1[(size_t)(kg * 8 + j) * HH + c]);
        *(short8*)&w1t[(size_t)c * DD + kg * 8] = v;
    }
    if (gtid < 2048) {   // w2t[64][256]
        int c = gtid & 63, kg = gtid >> 6;
        short8 v;
#pragma unroll
        for (int j = 0; j < 8; ++j) v[j] = (short)f2b(w2[(size_t)(kg * 8 + j) * LL + c]);
        *(short8*)&w2t[(size_t)c * HH + kg * 8] = v;
    }
}

// ---------------- K2: bucket edges by row (packed 8B slots) ----------------
__global__ __launch_bounds__(256) void k_bucket(const int* __restrict__ erow,
                                                const int* __restrict__ ecol,
                                                const float* __restrict__ ew,
                                                int* __restrict__ cnt,
                                                int2* __restrict__ slot) {
    int e = blockIdx.x * 256 + threadIdx.x;
    if (e >= EE) return;
    int r = erow[e];
    int pos = atomicAdd(&cnt[r], 1);
    if (pos < CAP) {
        slot[r * CAP + pos] = make_int2(ecol[e], __float_as_int(ew[e]));
    }
}

// ---------------- K3: GEMM1 (MFMA): xw1b[N,H] = xb[N,D] @ W1 (via w1t) ----------------
// grid (2,128): tile 64 rows x 128 cols; wave = 32x64
__global__ __launch_bounds__(256) void k_gemm1_mfma(const unsigned short* __restrict__ xb,
                                                    const unsigned short* __restrict__ w1t,
                                                    unsigned short* __restrict__ xw1b) {
    const int tid = threadIdx.x;
    const int wave = tid >> 6, lane = tid & 63;
    const int wr = wave >> 1, wc = wave & 1;
    const int lm = lane & 15, lh = lane >> 4;
    const int r0 = blockIdx.y * 64 + wr * 32;
    const int c0 = blockIdx.x * 128 + wc * 64;

    f32x4 acc[2][4];
#pragma unroll
    for (int m = 0; m < 2; ++m)
#pragma unroll
        for (int n = 0; n < 4; ++n) acc[m][n] = (f32x4){0.f, 0.f, 0.f, 0.f};

    for (int k0 = 0; k0 < DD; k0 += 32) {
        short8 a[2], b[4];
#pragma unroll
        for (int m = 0; m < 2; ++m)
            a[m] = *(const short8*)&xb[(size_t)(r0 + m * 16 + lm) * DD + k0 + lh * 8];
#pragma unroll
        for (int n = 0; n < 4; ++n)
            b[n] = *(const short8*)&w1t[(size_t)(c0 + n * 16 + lm) * DD + k0 + lh * 8];
#pragma unroll
        for (int m = 0; m < 2; ++m)
#pragma unroll
            for (int n = 0; n < 4; ++n)
                acc[m][n] = __builtin_amdgcn_mfma_f32_16x16x32_bf16(a[m], b[n], acc[m][n], 0, 0, 0);
    }
#pragma unroll
    for (int m = 0; m < 2; ++m)
#pragma unroll
        for (int n = 0; n < 4; ++n)
#pragma unroll
            for (int q = 0; q < 4; ++q) {
                int row = r0 + m * 16 + lh * 4 + q;
                int col = c0 + n * 16 + lm;
                xw1b[(size_t)row * HH + col] = f2b(acc[m][n][q]);
            }
}

// ---------------- K4: SpMM1 (half-wave gather) + block-level GEMM2 epilogue ----------------
// 4 waves = 4 rows; rows -> rowbuf LDS; barrier; wave 0 does 4-row GEMM2 via MFMA.
__global__ __launch_bounds__(256) void k_spmm1_gemm2(const int* __restrict__ cnt,
                                                     const int2* __restrict__ slot,
                                                     const unsigned short* __restrict__ src,
                                                     const unsigned short* __restrict__ w2t,
                                                     unsigned short* __restrict__ hw2b) {
    __shared__ unsigned short rowbuf[16][HH];  // rows 0-3 valid; 4-15 never read into valid C rows
    const int tid = threadIdx.x;
    const int wv = tid >> 6;
    const int row = blockIdx.x * 4 + wv;
    const int lane = tid & 63;
    const int half = lane >> 5;
    const int l32 = lane & 31;
    const int deg = min(cnt[row], CAP);
    const int base = row * CAP;

    float acc[8] = {};
    int i = 0;
    for (; i + 7 < deg; i += 8) {
#pragma unroll
        for (int s = 0; s < 4; ++s) {
            int2 sl = slot[base + i + s * 2 + half];
            float w = __int_as_float(sl.y);
            short8 u = *(const short8*)&src[(size_t)sl.x * HH + l32 * 8];
#pragma unroll
            for (int k = 0; k < 8; ++k)
                acc[k] = fmaf(w, b2f((unsigned short)u[k]), acc[k]);
        }
    }
    for (; i < deg; i += 2) {
        int idx = i + half;
        bool safe = idx < deg;
        int2 sl = slot[base + (safe ? idx : i)];
        float w = safe ? __int_as_float(sl.y) : 0.f;
        short8 u = *(const short8*)&src[(size_t)sl.x * HH + l32 * 8];
#pragma unroll
        for (int k = 0; k < 8; ++k)
            acc[k] = fmaf(w, b2f((unsigned short)u[k]), acc[k]);
    }
#pragma unroll
    for (int k = 0; k < 8; ++k) acc[k] += __shfl_xor(acc[k], 32);
    if (half == 0) {
        short8 o;
#pragma unroll
        for (int k = 0; k < 8; ++k) o[k] = (short)f2b(fmaxf(acc[k], 0.f));
        *(short8*)&rowbuf[wv][l32 * 8] = o;
    }
    __syncthreads();

    // wave 0: GEMM2 for the block's 4 rows. C rows 0-3 depend only on A rows 0-3.
    if (wv == 0) {
        const int lm = lane & 15, lh = lane >> 4;
        f32x4 c[4];
#pragma unroll
        for (int n = 0; n < 4; ++n) c[n] = (f32x4){0.f, 0.f, 0.f, 0.f};
        for (int k0 = 0; k0 < HH; k0 += 32) {
            short8 a = *(const short8*)&rowbuf[lm][k0 + lh * 8];
#pragma unroll
            for (int n = 0; n < 4; ++n) {
                short8 b = *(const short8*)&w2t[(size_t)(n * 16 + lm) * HH + k0 + lh * 8];
                c[n] = __builtin_amdgcn_mfma_f32_16x16x32_bf16(a, b, c[n], 0, 0, 0);
            }
        }
        // C layout: row = lh*4+q, col = lm. Valid rows 0-3 -> lanes 0-15 (lh==0), q=0..3.
        if (lh == 0) {
#pragma unroll
            for (int n = 0; n < 4; ++n)
#pragma unroll
                for (int q = 0; q < 4; ++q)
                    hw2b[(size_t)(blockIdx.x * 4 + q) * LL + n * 16 + lm] = f2b(c[n][q]);
        }
    }
}

// ---------------- K5: SpMM2: quarter-wave per edge, 8B loads, packed slots ----------------
__global__ __launch_bounds__(256) void k_spmm2_csr(const int* __restrict__ cnt,
                                                   const int2* __restrict__ slot,
                                                   const unsigned short* __restrict__ src,
                                                   unsigned short* __restrict__ zb) {
    const int tid = threadIdx.x;
    const int row = blockIdx.x * 4 + (tid >> 6);
    const int lane = tid & 63;
    const int qtr = lane >> 4;
    const int g = lane & 15;
    const int deg = min(cnt[row], CAP);
    const int base = row * CAP;

    float acc[4] = {};
    int i = 0;
    for (; i + 7 < deg; i += 8) {
#pragma unroll
        for (int s = 0; s < 2; ++s) {
            int2 sl = slot[base + i + s * 4 + qtr];
            float w = __int_as_float(sl.y);
            ushort4 u = *(const ushort4*)&src[(size_t)sl.x * LL + g * 4];
            acc[0] = fmaf(w, b2f(u.x), acc[0]); acc[1] = fmaf(w, b2f(u.y), acc[1]);
            acc[2] = fmaf(w, b2f(u.z), acc[2]); acc[3] = fmaf(w, b2f(u.w), acc[3]);
        }
    }
    for (; i < deg; i += 4) {
        int idx = i + qtr;
        bool safe = idx < deg;
        int2 sl = slot[base + (safe ? idx : i)];
        float w = safe ? __int_as_float(sl.y) : 0.f;
        ushort4 u = *(const ushort4*)&src[(size_t)sl.x * LL + g * 4];
        acc[0] = fmaf(w, b2f(u.x), acc[0]); acc[1] = fmaf(w, b2f(u.y), acc[1]);
        acc[2] = fmaf(w, b2f(u.z), acc[2]); acc[3] = fmaf(w, b2f(u.w), acc[3]);
    }
#pragma unroll
    for (int k = 0; k < 4; ++k) {
        acc[k] += __shfl_xor(acc[k], 16);
        acc[k] += __shfl_xor(acc[k], 32);
    }
    if (lane < 16) {
        ushort4 o;
        o.x = f2b(fmaxf(acc[0], 0.f)); o.y = f2b(fmaxf(acc[1], 0.f));
        o.z = f2b(fmaxf(acc[2], 0.f)); o.w = f2b(fmaxf(acc[3], 0.f));
        *(ushort4*)&zb[(size_t)row * LL + g * 4] = o;
    }
}

// ---------------- K6 decode: 64x256 tiles, MFMA + 16-row LDS chunks + NT stores ----------------
__global__ __launch_bounds__(256) void k_decode(const unsigned short* __restrict__ zb,
                                                float* __restrict__ out) {
    __shared__ float ls[16 * DSTR];
    const int tid = threadIdx.x;
    const int wave = tid >> 6, lane = tid & 63;
    const int bi = blockIdx.y, bj = blockIdx.x;
    const int lm = lane & 15, lh = lane >> 4;
    const int rA = bi * 64;
    const int cB = bj * 256 + wave * 64;

    short8 a[4][2], b[4][2];
#pragma unroll
    for (int m = 0; m < 4; ++m)
#pragma unroll
        for (int s = 0; s < 2; ++s)
            a[m][s] = *(const short8*)&zb[(size_t)(rA + m * 16 + lm) * LL + s * 32 + lh * 8];
#pragma unroll
    for (int n = 0; n < 4; ++n)
#pragma unroll
        for (int s = 0; s < 2; ++s)
            b[n][s] = *(const short8*)&zb[(size_t)(cB + n * 16 + lm) * LL + s * 32 + lh * 8];

    f32x4 acc[4][4];
#pragma unroll
    for (int m = 0; m < 4; ++m)
#pragma unroll
        for (int n = 0; n < 4; ++n) acc[m][n] = (f32x4){0.f, 0.f, 0.f, 0.f};

#pragma unroll
    for (int m = 0; m < 4; ++m)
#pragma unroll
        for (int n = 0; n < 4; ++n)
#pragma unroll
            for (int s = 0; s < 2; ++s)
                acc[m][n] = __builtin_amdgcn_mfma_f32_16x16x32_bf16(
                    a[m][s], b[n][s], acc[m][n], 0, 0, 0);

    const float SCALE = 1.0f - 2.0f * 1e-7f;
    const float BIAS = 1e-7f * SCALE;
    const int slr = tid >> 4;          // store row in 16-row group
    const int scol = (tid & 15) * 4;   // store col base
#pragma unroll
    for (int m = 0; m < 4; ++m) {
#pragma unroll
        for (int n = 0; n < 4; ++n)
#pragma unroll
            for (int q = 0; q < 4; ++q) {
                float xv = acc[m][n][q];
                float sig = __fdividef(1.0f, 1.0f + __expf(-xv));
                float val = fmaf(sig, SCALE, BIAS);
                int lr = lh * 4 + q;                   // 0..15 within group
                int lc = wave * 64 + n * 16 + lm;      // 0..255
                ls[lr * DSTR + lc] = val;
            }
        __syncthreads();
        const size_t rowbase = (size_t)(rA + m * 16 + slr) * NN + bj * 256;
#pragma unroll
        for (int it = 0; it < 4; ++it) {
            int col = it * 64 + scol;
            f32x4 v = *(const f32x4*)&ls[slr * DSTR + col];
            __builtin_nontemporal_store(v, (f32x4*)&out[rowbase + col]);
        }
        __syncthreads();
    }
}

// ---------------- launch ----------------
extern "C" void kernel_launch(void* const* d_in, const int* in_sizes, int n_in,
                              void* d_out, int out_size, void* d_ws, size_t ws_size,
                              hipStream_t stream) {
    const float* x    = (const float*)d_in[0];
    const int*   erow = (const int*)d_in[1];
    const int*   ecol = (const int*)d_in[2];
    const float* ew   = (const float*)d_in[3];
    const float* w1   = (const float*)d_in[4];
    const float* w2   = (const float*)d_in[5];
    float* out = (float*)d_out;

    char* p = (char*)d_ws;
    unsigned short* xb    = (unsigned short*)p; p += (size_t)NN * DD * 2;  // 8 MB
    unsigned short* w1t   = (unsigned short*)p; p += (size_t)HH * DD * 2;  // 256 KB
    unsigned short* w2t   = (unsigned short*)p; p += (size_t)LL * HH * 2;  // 32 KB
    unsigned short* xw1b  = (unsigned short*)p; p += (size_t)NN * HH * 2;  // 4 MB
    unsigned short* hw2b  = (unsigned short*)p; p += (size_t)NN * LL * 2;  // 1 MB
    unsigned short* zb    = (unsigned short*)p; p += (size_t)NN * LL * 2;  // 1 MB
    int*   cnt   = (int*)p;   p += (size_t)NN * 4;        // 32 KB
    int2*  slot  = (int2*)p;  p += (size_t)NN * CAP * 8;  // 6 MB

    k_prep<<<2048, 256, 0, stream>>>(x, w1, w2, xb, w1t, w2t, cnt);
    k_bucket<<<EE / 256, 256, 0, stream>>>(erow, ecol, ew, cnt, slot);
    k_gemm1_mfma<<<dim3(2, 128), 256, 0, stream>>>(xb, w1t, xw1b);
    k_spmm1_gemm2<<<NN / 4, 256, 0, stream>>>(cnt, slot, xw1b, w2t, hw2b);
    k_spmm2_csr<<<NN / 4, 256, 0, stream>>>(cnt, slot, hw2b, zb);
    k_decode<<<dim3(32, 128), 256, 0, stream>>>(zb, out);
}

// Round 14
// 112.910 us; speedup vs baseline: 1.0142x; 1.0142x over previous
//
#include <hip/hip_runtime.h>
#include <hip/hip_bf16.h>

#define NN 8192
#define DD 512
#define HH 256
#define LL 64
#define EE 262144
#define CAP 96
#define DSTR 260   // decode LDS row stride (floats): 16x260 f32 = 16.6 KB

typedef __attribute__((ext_vector_type(8))) short short8;
typedef __attribute__((ext_vector_type(4))) float f32x4;

__device__ __forceinline__ unsigned short f2b(float f) {
    __hip_bfloat16 b = __float2bfloat16(f);
    return *(unsigned short*)&b;
}
__device__ __forceinline__ float b2f(unsigned short u) {
    union { unsigned int i; float f; } c; c.i = ((unsigned int)u) << 16; return c.f;
}

// ---------------- K1 prep: zero cnt + cast x->bf16 + transpose/cast W1,W2 ----------------
__global__ __launch_bounds__(256) void k_prep(const float* __restrict__ x,
                                              const float* __restrict__ w1,
                                              const float* __restrict__ w2,
                                              unsigned short* __restrict__ xb,
                                              unsigned short* __restrict__ w1t,
                                              unsigned short* __restrict__ w2t,
                                              int* __restrict__ cnt) {
    const int gtid = blockIdx.x * 256 + threadIdx.x;  // 0..524287
#pragma unroll
    for (int it = 0; it < 2; ++it) {
        int i = gtid + it * 524288;
        float4 v = ((const float4*)x)[i];
        ushort4 o; o.x = f2b(v.x); o.y = f2b(v.y); o.z = f2b(v.z); o.w = f2b(v.w);
        ((ushort4*)xb)[i] = o;
    }
    if (gtid < NN / 4) ((int4*)cnt)[gtid] = make_int4(0, 0, 0, 0);
    if (gtid < 16384) {  // w1t[256][512]
        int c = gtid & 255, kg = gtid >> 8;
        short8 v;
#pragma unroll
        for (int j = 0; j < 8; ++j) v[j] = (short)f2b(w1[(size_t)(kg * 8 + j) * HH + c]);
        *(short8*)&w1t[(size_t)c * DD + kg * 8] = v;
    }
    if (gtid < 2048) {   // w2t[64][256]
        int c = gtid & 63, kg = gtid >> 6;
        short8 v;
#pragma unroll
        for (int j = 0; j < 8; ++j) v[j] = (short)f2b(w2[(size_t)(kg * 8 + j) * LL + c]);
        *(short8*)&w2t[(size_t)c * HH + kg * 8] = v;
    }
}

// ---------------- K2: bucket edges by row (packed 8B slots) ----------------
__global__ __launch_bounds__(256) void k_bucket(const int* __restrict__ erow,
                                                const int* __restrict__ ecol,
                                                const float* __restrict__ ew,
                                                int* __restrict__ cnt,
                                                int2* __restrict__ slot) {
    int e = blockIdx.x * 256 + threadIdx.x;
    if (e >= EE) return;
    int r = erow[e];
    int pos = atomicAdd(&cnt[r], 1);
    if (pos < CAP) {
        slot[r * CAP + pos] = make_int2(ecol[e], __float_as_int(ew[e]));
    }
}

// ---------------- K3: GEMM1 (MFMA): xw1b[N,H] = xb[N,D] @ W1 (via w1t) ----------------
// grid (2,128): tile 64 rows x 128 cols; wave = 32x64
__global__ __launch_bounds__(256) void k_gemm1_mfma(const unsigned short* __restrict__ xb,
                                                    const unsigned short* __restrict__ w1t,
                                                    unsigned short* __restrict__ xw1b) {
    const int tid = threadIdx.x;
    const int wave = tid >> 6, lane = tid & 63;
    const int wr = wave >> 1, wc = wave & 1;
    const int lm = lane & 15, lh = lane >> 4;
    const int r0 = blockIdx.y * 64 + wr * 32;
    const int c0 = blockIdx.x * 128 + wc * 64;

    f32x4 acc[2][4];
#pragma unroll
    for (int m = 0; m < 2; ++m)
#pragma unroll
        for (int n = 0; n < 4; ++n) acc[m][n] = (f32x4){0.f, 0.f, 0.f, 0.f};

    for (int k0 = 0; k0 < DD; k0 += 32) {
        short8 a[2], b[4];
#pragma unroll
        for (int m = 0; m < 2; ++m)
            a[m] = *(const short8*)&xb[(size_t)(r0 + m * 16 + lm) * DD + k0 + lh * 8];
#pragma unroll
        for (int n = 0; n < 4; ++n)
            b[n] = *(const short8*)&w1t[(size_t)(c0 + n * 16 + lm) * DD + k0 + lh * 8];
#pragma unroll
        for (int m = 0; m < 2; ++m)
#pragma unroll
            for (int n = 0; n < 4; ++n)
                acc[m][n] = __builtin_amdgcn_mfma_f32_16x16x32_bf16(a[m], b[n], acc[m][n], 0, 0, 0);
    }
#pragma unroll
    for (int m = 0; m < 2; ++m)
#pragma unroll
        for (int n = 0; n < 4; ++n)
#pragma unroll
            for (int q = 0; q < 4; ++q) {
                int row = r0 + m * 16 + lh * 4 + q;
                int col = c0 + n * 16 + lm;
                xw1b[(size_t)row * HH + col] = f2b(acc[m][n][q]);
            }
}

// ---------------- K4: SpMM1: half-wave per edge, 16B loads, packed slots ----------------
__global__ __launch_bounds__(256) void k_spmm1_csr(const int* __restrict__ cnt,
                                                   const int2* __restrict__ slot,
                                                   const unsigned short* __restrict__ src,
                                                   unsigned short* __restrict__ dst) {
    const int tid = threadIdx.x;
    const int row = blockIdx.x * 4 + (tid >> 6);
    const int lane = tid & 63;
    const int half = lane >> 5;
    const int l32 = lane & 31;
    const int deg = min(cnt[row], CAP);
    const int base = row * CAP;

    float acc[8] = {};
    int i = 0;
    for (; i + 7 < deg; i += 8) {
#pragma unroll
        for (int s = 0; s < 4; ++s) {
            int2 sl = slot[base + i + s * 2 + half];
            float w = __int_as_float(sl.y);
            short8 u = *(const short8*)&src[(size_t)sl.x * HH + l32 * 8];
#pragma unroll
            for (int k = 0; k < 8; ++k)
                acc[k] = fmaf(w, b2f((unsigned short)u[k]), acc[k]);
        }
    }
    for (; i < deg; i += 2) {
        int idx = i + half;
        bool safe = idx < deg;
        int2 sl = slot[base + (safe ? idx : i)];
        float w = safe ? __int_as_float(sl.y) : 0.f;
        short8 u = *(const short8*)&src[(size_t)sl.x * HH + l32 * 8];
#pragma unroll
        for (int k = 0; k < 8; ++k)
            acc[k] = fmaf(w, b2f((unsigned short)u[k]), acc[k]);
    }
#pragma unroll
    for (int k = 0; k < 8; ++k) acc[k] += __shfl_xor(acc[k], 32);
    if (half == 0) {
        short8 o;
#pragma unroll
        for (int k = 0; k < 8; ++k) o[k] = (short)f2b(fmaxf(acc[k], 0.f));
        *(short8*)&dst[(size_t)row * HH + l32 * 8] = o;
    }
}

// ---------------- K5: GEMM2 (MFMA): hw2b[N,L] = haccb[N,H] @ W2 (via w2t) ----------------
// grid 128: block tile 64 rows; wave = 16 rows x 64 cols
__global__ __launch_bounds__(256) void k_gemm2_mfma(const unsigned short* __restrict__ haccb,
                                                    const unsigned short* __restrict__ w2t,
                                                    unsigned short* __restrict__ hw2b) {
    const int tid = threadIdx.x;
    const int wave = tid >> 6, lane = tid & 63;
    const int lm = lane & 15, lh = lane >> 4;
    const int r0 = blockIdx.x * 64 + wave * 16;

    f32x4 acc[4];
#pragma unroll
    for (int n = 0; n < 4; ++n) acc[n] = (f32x4){0.f, 0.f, 0.f, 0.f};

    for (int k0 = 0; k0 < HH; k0 += 32) {
        short8 a = *(const short8*)&haccb[(size_t)(r0 + lm) * HH + k0 + lh * 8];
#pragma unroll
        for (int n = 0; n < 4; ++n) {
            short8 b = *(const short8*)&w2t[(size_t)(n * 16 + lm) * HH + k0 + lh * 8];
            acc[n] = __builtin_amdgcn_mfma_f32_16x16x32_bf16(a, b, acc[n], 0, 0, 0);
        }
    }
#pragma unroll
    for (int n = 0; n < 4; ++n)
#pragma unroll
        for (int q = 0; q < 4; ++q) {
            int row = r0 + lh * 4 + q;
            int col = n * 16 + lm;
            hw2b[(size_t)row * LL + col] = f2b(acc[n][q]);
        }
}

// ---------------- K6: SpMM2: quarter-wave per edge, 8B loads, packed slots ----------------
__global__ __launch_bounds__(256) void k_spmm2_csr(const int* __restrict__ cnt,
                                                   const int2* __restrict__ slot,
                                                   const unsigned short* __restrict__ src,
                                                   unsigned short* __restrict__ zb) {
    const int tid = threadIdx.x;
    const int row = blockIdx.x * 4 + (tid >> 6);
    const int lane = tid & 63;
    const int qtr = lane >> 4;
    const int g = lane & 15;
    const int deg = min(cnt[row], CAP);
    const int base = row * CAP;

    float acc[4] = {};
    int i = 0;
    for (; i + 7 < deg; i += 8) {
#pragma unroll
        for (int s = 0; s < 2; ++s) {
            int2 sl = slot[base + i + s * 4 + qtr];
            float w = __int_as_float(sl.y);
            ushort4 u = *(const ushort4*)&src[(size_t)sl.x * LL + g * 4];
            acc[0] = fmaf(w, b2f(u.x), acc[0]); acc[1] = fmaf(w, b2f(u.y), acc[1]);
            acc[2] = fmaf(w, b2f(u.z), acc[2]); acc[3] = fmaf(w, b2f(u.w), acc[3]);
        }
    }
    for (; i < deg; i += 4) {
        int idx = i + qtr;
        bool safe = idx < deg;
        int2 sl = slot[base + (safe ? idx : i)];
        float w = safe ? __int_as_float(sl.y) : 0.f;
        ushort4 u = *(const ushort4*)&src[(size_t)sl.x * LL + g * 4];
        acc[0] = fmaf(w, b2f(u.x), acc[0]); acc[1] = fmaf(w, b2f(u.y), acc[1]);
        acc[2] = fmaf(w, b2f(u.z), acc[2]); acc[3] = fmaf(w, b2f(u.w), acc[3]);
    }
#pragma unroll
    for (int k = 0; k < 4; ++k) {
        acc[k] += __shfl_xor(acc[k], 16);
        acc[k] += __shfl_xor(acc[k], 32);
    }
    if (lane < 16) {
        ushort4 o;
        o.x = f2b(fmaxf(acc[0], 0.f)); o.y = f2b(fmaxf(acc[1], 0.f));
        o.z = f2b(fmaxf(acc[2], 0.f)); o.w = f2b(fmaxf(acc[3], 0.f));
        *(ushort4*)&zb[(size_t)row * LL + g * 4] = o;
    }
}

// ---------------- K7 decode: 64x256 tiles, MFMA + 16-row LDS chunks + NT stores ----------------
__global__ __launch_bounds__(256) void k_decode(const unsigned short* __restrict__ zb,
                                                float* __restrict__ out) {
    __shared__ float ls[16 * DSTR];
    const int tid = threadIdx.x;
    const int wave = tid >> 6, lane = tid & 63;
    const int bi = blockIdx.y, bj = blockIdx.x;
    const int lm = lane & 15, lh = lane >> 4;
    const int rA = bi * 64;
    const int cB = bj * 256 + wave * 64;

    short8 a[4][2], b[4][2];
#pragma unroll
    for (int m = 0; m < 4; ++m)
#pragma unroll
        for (int s = 0; s < 2; ++s)
            a[m][s] = *(const short8*)&zb[(size_t)(rA + m * 16 + lm) * LL + s * 32 + lh * 8];
#pragma unroll
    for (int n = 0; n < 4; ++n)
#pragma unroll
        for (int s = 0; s < 2; ++s)
            b[n][s] = *(const short8*)&zb[(size_t)(cB + n * 16 + lm) * LL + s * 32 + lh * 8];

    f32x4 acc[4][4];
#pragma unroll
    for (int m = 0; m < 4; ++m)
#pragma unroll
        for (int n = 0; n < 4; ++n) acc[m][n] = (f32x4){0.f, 0.f, 0.f, 0.f};

#pragma unroll
    for (int m = 0; m < 4; ++m)
#pragma unroll
        for (int n = 0; n < 4; ++n)
#pragma unroll
            for (int s = 0; s < 2; ++s)
                acc[m][n] = __builtin_amdgcn_mfma_f32_16x16x32_bf16(
                    a[m][s], b[n][s], acc[m][n], 0, 0, 0);

    const float SCALE = 1.0f - 2.0f * 1e-7f;
    const float BIAS = 1e-7f * SCALE;
    const int slr = tid >> 4;          // store row in 16-row group
    const int scol = (tid & 15) * 4;   // store col base
#pragma unroll
    for (int m = 0; m < 4; ++m) {
#pragma unroll
        for (int n = 0; n < 4; ++n)
#pragma unroll
            for (int q = 0; q < 4; ++q) {
                float xv = acc[m][n][q];
                float sig = __fdividef(1.0f, 1.0f + __expf(-xv));
                float val = fmaf(sig, SCALE, BIAS);
                int lr = lh * 4 + q;                   // 0..15 within group
                int lc = wave * 64 + n * 16 + lm;      // 0..255
                ls[lr * DSTR + lc] = val;
            }
        __syncthreads();
        const size_t rowbase = (size_t)(rA + m * 16 + slr) * NN + bj * 256;
#pragma unroll
        for (int it = 0; it < 4; ++it) {
            int col = it * 64 + scol;
            f32x4 v = *(const f32x4*)&ls[slr * DSTR + col];
            __builtin_nontemporal_store(v, (f32x4*)&out[rowbase + col]);
        }
        __syncthreads();
    }
}

// ---------------- launch ----------------
extern "C" void kernel_launch(void* const* d_in, const int* in_sizes, int n_in,
                              void* d_out, int out_size, void* d_ws, size_t ws_size,
                              hipStream_t stream) {
    const float* x    = (const float*)d_in[0];
    const int*   erow = (const int*)d_in[1];
    const int*   ecol = (const int*)d_in[2];
    const float* ew   = (const float*)d_in[3];
    const float* w1   = (const float*)d_in[4];
    const float* w2   = (const float*)d_in[5];
    float* out = (float*)d_out;

    char* p = (char*)d_ws;
    unsigned short* xb    = (unsigned short*)p; p += (size_t)NN * DD * 2;  // 8 MB
    unsigned short* w1t   = (unsigned short*)p; p += (size_t)HH * DD * 2;  // 256 KB
    unsigned short* w2t   = (unsigned short*)p; p += (size_t)LL * HH * 2;  // 32 KB
    unsigned short* xw1b  = (unsigned short*)p; p += (size_t)NN * HH * 2;  // 4 MB
    unsigned short* haccb = (unsigned short*)p; p += (size_t)NN * HH * 2;  // 4 MB
    unsigned short* hw2b  = (unsigned short*)p; p += (size_t)NN * LL * 2;  // 1 MB
    unsigned short* zb    = (unsigned short*)p; p += (size_t)NN * LL * 2;  // 1 MB
    int*   cnt   = (int*)p;   p += (size_t)NN * 4;        // 32 KB
    int2*  slot  = (int2*)p;  p += (size_t)NN * CAP * 8;  // 6 MB

    k_prep<<<2048, 256, 0, stream>>>(x, w1, w2, xb, w1t, w2t, cnt);
    k_bucket<<<EE / 256, 256, 0, stream>>>(erow, ecol, ew, cnt, slot);
    k_gemm1_mfma<<<dim3(2, 128), 256, 0, stream>>>(xb, w1t, xw1b);
    k_spmm1_csr<<<NN / 4, 256, 0, stream>>>(cnt, slot, xw1b, haccb);
    k_gemm2_mfma<<<128, 256, 0, stream>>>(haccb, w2t, hw2b);
    k_spmm2_csr<<<NN / 4, 256, 0, stream>>>(cnt, slot, hw2b, zb);
    k_decode<<<dim3(32, 128), 256, 0, stream>>>(zb, out);
}